// Round 1
// baseline (322.182 us; speedup 1.0000x reference)
//
#include <hip/hip_runtime.h>
#include <math.h>

#define PI_F 3.14159265358979323846f

// Shapes: B=4, X=Y=Z=64, CIN=COUT=32, modes 16.
// Reference transforms (Y, Z, CIN); crop x<16, ky<16, kz<16; einsum over ki;
// inverse over (ky->y, kz->z, o->co); real part; output zero for x>=16.
//
//  K1 z-DFT   : x[b,x<16,y,z,i] -> T1[b,x,y,kz<16,i]   (i-half split, 4 blk/CU)
//  K2 y-DFT   : T1 -> XH[b,x,ky<16,kz,i]               (kz split x2, 4 blk/CU)
//  K3 fused   : i-DFT(32) + w-mul + o-IDFT(32): XH -> G[b,x,ky,kz,co]
//               (kz split x4 -> grid 1024, 4 blk/CU; ki-sum split across
//                thread halves with LDS combine)
//  K4 fused   : z-IDFT + y-IDFT + Re + 1/131072 + zero-fill -> out
//               (co split x2 for active blocks, 4 blk/CU)

// ---------------- K1: forward z-DFT ----------------------------------------
// grid 1024 = (b4, x16, yg8, ih2); block 256; tile 2kz x 4i per thread.
__global__ __launch_bounds__(256) void k_dft_z(const float* __restrict__ x,
                                               float2* __restrict__ T1) {
    int bid = blockIdx.x;
    int ih = bid & 1, yg = (bid >> 1) & 7, xx = (bid >> 4) & 15, b = bid >> 8;
    __shared__ float  sx[8192];      // [y8][z64][i16] 32KB
    __shared__ float2 twt[1024];     // [z][kz16] 8KB
    float4* sx4 = (float4*)sx;
    const float4* src4 = (const float4*)(x + (size_t)((b * 64 + xx) * 64 + yg * 8) * 2048) + ih * 4;
    #pragma unroll
    for (int t = threadIdx.x; t < 2048; t += 256) {
        int i4 = t & 3, z = (t >> 2) & 63, y = t >> 8;
        sx4[(y * 64 + z) * 4 + i4] = src4[(size_t)y * 512 + z * 8 + i4];
    }
    const float cn = -2.0f * PI_F / 64.0f;
    for (int t = threadIdx.x; t < 1024; t += 256) {
        int z = t >> 4, kz = t & 15;
        float s, c; sincosf(cn * (float)((z * kz) & 63), &s, &c);
        twt[t] = make_float2(c, s);
    }
    __syncthreads();
    int ig = threadIdx.x & 3, kz2 = (threadIdx.x >> 2) & 7, y8 = threadIdx.x >> 5;
    float ar0[4], ai0[4], ar1[4], ai1[4];
    #pragma unroll
    for (int j = 0; j < 4; j++) { ar0[j] = ai0[j] = ar1[j] = ai1[j] = 0.f; }
    const float4* twv = (const float4*)twt;   // [z][8]: (c0,s0,c1,s1) per kz-pair
    #pragma unroll 8
    for (int z = 0; z < 64; z++) {
        float4 va = sx4[(y8 * 64 + z) * 4 + ig];
        float4 tp = twv[z * 8 + kz2];
        float v[4] = {va.x, va.y, va.z, va.w};
        #pragma unroll
        for (int j = 0; j < 4; j++) {
            ar0[j] = fmaf(v[j], tp.x, ar0[j]);
            ai0[j] = fmaf(v[j], tp.y, ai0[j]);
            ar1[j] = fmaf(v[j], tp.z, ar1[j]);
            ai1[j] = fmaf(v[j], tp.w, ai1[j]);
        }
    }
    int y = yg * 8 + y8, kz0 = kz2 * 2, i0 = ih * 16 + ig * 4;
    float2* dst = T1 + (size_t)((b * 16 + xx) * 64 + y) * 512;
    float4* d0 = (float4*)(dst + kz0 * 32 + i0);
    d0[0] = make_float4(ar0[0], ai0[0], ar0[1], ai0[1]);
    d0[1] = make_float4(ar0[2], ai0[2], ar0[3], ai0[3]);
    float4* d1 = (float4*)(dst + (kz0 + 1) * 32 + i0);
    d1[0] = make_float4(ar1[0], ai1[0], ar1[1], ai1[1]);
    d1[1] = make_float4(ar1[2], ai1[2], ar1[3], ai1[3]);
}

// ---------------- K2: forward y-DFT ----------------------------------------
// grid 1024 = (b4, x16, kzg8, ih2); block 256; 1ky x 2i per thread.
__global__ __launch_bounds__(256) void k_dft_y(const float2* __restrict__ T1,
                                               float2* __restrict__ XH) {
    int bid = blockIdx.x;
    int ih = bid & 1, kzg = (bid >> 1) & 7, xx = (bid >> 4) & 15, b = bid >> 8;
    __shared__ float4 sT4[2 * 576];  // [kz2][y(stride 9)][i4 8] ~18.4KB
    __shared__ float2 twt[1024];     // [y][ky16] 8KB
    const float4* Tg4 = (const float4*)T1;
    size_t gbase = (size_t)(b * 16 + xx) * 64 * 256;
    #pragma unroll
    for (int t = threadIdx.x; t < 1024; t += 256) {
        int i4 = t & 7, kzl = (t >> 3) & 1, y = t >> 4;
        sT4[kzl * 576 + y * 9 + i4] =
            Tg4[gbase + (size_t)y * 256 + (kzg * 2 + kzl) * 16 + ih * 8 + i4];
    }
    const float cn = -2.0f * PI_F / 64.0f;
    for (int t = threadIdx.x; t < 1024; t += 256) {
        int y = t >> 4, ky = t & 15;
        float s, c; sincosf(cn * (float)((y * ky) & 63), &s, &c);
        twt[t] = make_float2(c, s);
    }
    __syncthreads();
    int ig = threadIdx.x & 7, kzl = (threadIdx.x >> 3) & 1, ky = threadIdx.x >> 4;
    float ar0 = 0.f, ai0 = 0.f, ar1 = 0.f, ai1 = 0.f;
    #pragma unroll 8
    for (int y = 0; y < 64; y++) {
        float4 a  = sT4[kzl * 576 + y * 9 + ig];   // (xr0,xi0,xr1,xi1)
        float2 tp = twt[y * 16 + ky];
        ar0 += a.x * tp.x - a.y * tp.y;
        ai0 += a.x * tp.y + a.y * tp.x;
        ar1 += a.z * tp.x - a.w * tp.y;
        ai1 += a.z * tp.y + a.w * tp.x;
    }
    int kz = kzg * 2 + kzl;
    float2* dp = XH + (((size_t)(b * 16 + xx) * 16 + ky) * 16 + kz) * 32 + ih * 16 + ig * 2;
    *(float4*)dp = make_float4(ar0, ai0, ar1, ai1);
}

// ---------------- K3: fused i-DFT + w-mul + o-IDFT -------------------------
// grid 1024 = (x16, ky16, kzq4); block 256; all 4 b in-block (weights stay
// read-once); kz is a pure batch axis for all three phases.
__global__ __launch_bounds__(256) void k_mid(const float2* __restrict__ XH,
                                             const float* __restrict__ wr,
                                             const float* __restrict__ wi,
                                             float2* __restrict__ G) {
    int bid = blockIdx.x;
    int kzq = bid & 3, ky = (bid >> 2) & 15, xx = bid >> 6;
    __shared__ float2 sA[4 * 132];   // [b][kz4(stride 33)][i32] ; reused as F[b][kz][o]
    __shared__ float2 sB[4 * 192];   // [b][ki32(stride 6)][kz4] ; reused as combine scratch
    __shared__ float2 twt[1024];     // [m][k] = exp(-2pi i mk/32)
    for (int t = threadIdx.x; t < 512; t += 256) {
        int i = t & 31, kz = (t >> 5) & 3, b = t >> 7;
        sA[b * 132 + kz * 33 + i] =
            XH[(((size_t)(b * 16 + xx) * 16 + ky) * 16 + kzq * 4 + kz) * 32 + i];
    }
    const float cn32 = -2.0f * PI_F / 32.0f;
    for (int t = threadIdx.x; t < 1024; t += 256) {
        int m = t >> 5, k = t & 31;
        float s, c; sincosf(cn32 * (float)((m * k) & 31), &s, &c);
        twt[t] = make_float2(c, s);
    }
    __syncthreads();
    const float4* twv = (const float4*)twt;
    // phase 1: X2[b][ki][kz] = sum_i tw[ki,i] * XH[b][kz][i]  (2ki x 1kz per thread)
    {
        int kz = threadIdx.x & 3, kig = (threadIdx.x >> 2) & 15, b = threadIdx.x >> 6;
        float xr0 = 0.f, xi0 = 0.f, xr1 = 0.f, xi1 = 0.f;
        #pragma unroll 8
        for (int i = 0; i < 32; i++) {
            float2 a  = sA[b * 132 + kz * 33 + i];
            float4 tp = twv[i * 16 + kig];         // (c,s) for ki=2kig, 2kig+1
            xr0 += a.x * tp.x - a.y * tp.y;
            xi0 += a.x * tp.y + a.y * tp.x;
            xr1 += a.x * tp.z - a.y * tp.w;
            xi1 += a.x * tp.w + a.y * tp.z;
        }
        sB[b * 192 + (kig * 2) * 6 + kz]     = make_float2(xr0, xi0);
        sB[b * 192 + (kig * 2 + 1) * 6 + kz] = make_float2(xr1, xi1);
    }
    __syncthreads();
    // phase 2: F[b][kz][o] = sum_ki X2[b][ki][kz] * w[ki,o]
    // thread = (o32, b4, kih2): each half sums 16 ki over all 4 kz; LDS combine.
    int o = threadIdx.x & 31, b2 = (threadIdx.x >> 5) & 3, kih = threadIdx.x >> 7;
    float Fr[4], Fi[4];
    {
        #pragma unroll
        for (int q = 0; q < 4; q++) { Fr[q] = Fi[q] = 0.f; }
        const float4* sB4 = (const float4*)sB;     // f4 stride 3 per ki
        int wofs = xx * 256 + ky * 16 + kzq * 4;
        #pragma unroll 4
        for (int kk = 0; kk < 16; kk++) {
            int ki = kih * 16 + kk;
            float4 a01 = sB4[b2 * 96 + ki * 3];
            float4 a23 = sB4[b2 * 96 + ki * 3 + 1];
            float4 w4r = *(const float4*)(wr + (size_t)(ki * 32 + o) * 4096 + wofs);
            float4 w4i = *(const float4*)(wi + (size_t)(ki * 32 + o) * 4096 + wofs);
            float xr[4]  = {a01.x, a01.z, a23.x, a23.z};
            float xi[4]  = {a01.y, a01.w, a23.y, a23.w};
            float wrv[4] = {w4r.x, w4r.y, w4r.z, w4r.w};
            float wiv[4] = {w4i.x, w4i.y, w4i.z, w4i.w};
            #pragma unroll
            for (int q = 0; q < 4; q++) {
                Fr[q] += xr[q] * wrv[q] - xi[q] * wiv[q];
                Fi[q] += xr[q] * wiv[q] + xi[q] * wrv[q];
            }
        }
    }
    __syncthreads();                 // all sB reads done; reuse sB as scratch
    float2* scratch = sB;            // needs 512 f2 <= 768
    if (kih == 1) {
        #pragma unroll
        for (int q = 0; q < 4; q++)
            scratch[(b2 * 32 + o) * 4 + q] = make_float2(Fr[q], Fi[q]);
    }
    __syncthreads();
    if (kih == 0) {
        #pragma unroll
        for (int q = 0; q < 4; q++) {
            float2 p = scratch[(b2 * 32 + o) * 4 + q];
            sA[b2 * 132 + q * 33 + o] = make_float2(Fr[q] + p.x, Fi[q] + p.y);
        }
    }
    __syncthreads();
    // phase 3: G[b][kz][co] = sum_o conj(tw[co,o]) * F[b][kz][o] (2co x 1kz per thread)
    {
        int kz = threadIdx.x & 3, cog = (threadIdx.x >> 2) & 15, b = threadIdx.x >> 6;
        float gr0 = 0.f, gi0 = 0.f, gr1 = 0.f, gi1 = 0.f;
        #pragma unroll 8
        for (int oo = 0; oo < 32; oo++) {
            float2 f  = sA[b * 132 + kz * 33 + oo];
            float4 tp = twv[oo * 16 + cog];
            gr0 += f.x * tp.x + f.y * tp.y;
            gi0 += f.y * tp.x - f.x * tp.y;
            gr1 += f.x * tp.z + f.y * tp.w;
            gi1 += f.y * tp.z - f.x * tp.w;
        }
        float2* dp = G + (((size_t)(b * 16 + xx) * 16 + ky) * 16 + kzq * 4 + kz) * 32 + cog * 2;
        *(float4*)dp = make_float4(gr0, gi0, gr1, gi1);
    }
}

// ---------------- K4: fused z-IDFT + y-IDFT + Re + scale + zero-fill -------
// grid 4096 = (b4, x64, zc8, ch2); block 256. x>=16: ch0 fills full co, ch1 no-op.
__global__ __launch_bounds__(256) void k_idft_zy(const float2* __restrict__ G,
                                                 float* __restrict__ out) {
    int bid = blockIdx.x;
    int ch = bid & 1, zc = (bid >> 1) & 7, xx = (bid >> 4) & 63, b = bid >> 10;
    float* dstb = out + (size_t)(b * 64 + xx) * 131072;   // [y][z][co]
    if (xx >= 16) {
        if (ch) return;
        float4* d4 = (float4*)dstb;
        for (int t = threadIdx.x; t < 4096; t += 256) {
            int y = t >> 6, r = t & 63;
            d4[(size_t)y * 512 + zc * 64 + r] = make_float4(0.f, 0.f, 0.f, 0.f);
        }
        return;
    }
    __shared__ float2 sH[128 * 18];  // row R=ky*8+dz, stride 18, [co16]  ~18.4KB
    __shared__ float2 twy[1024];     // [ky][y] 8KB
    __shared__ float2 twz[8 * 17];   // [dz][kz] padded
    const float cp = 2.0f * PI_F / 64.0f;
    for (int t = threadIdx.x; t < 1024; t += 256) {
        int ky = t >> 6, y = t & 63;
        float s, c; sincosf(cp * (float)((ky * y) & 63), &s, &c);
        twy[t] = make_float2(c, s);
    }
    if (threadIdx.x < 128) {
        int dz = threadIdx.x >> 4, kz = threadIdx.x & 15;
        int z = zc * 8 + dz;
        float s, c; sincosf(cp * (float)((kz * z) & 63), &s, &c);
        twz[dz * 17 + kz] = make_float2(c, s);
    }
    __syncthreads();
    // phase Z: H[ky][dz][co16] = sum_kz twz[dz,kz] * G[ky][kz][co-half]
    {
        int coq = threadIdx.x & 1, dz = (threadIdx.x >> 1) & 7, ky = threadIdx.x >> 4;
        const float2* Gb = G + ((size_t)(b * 16 + xx) * 16 + ky) * 512 + ch * 16 + coq * 8;
        float Hr[8], Hi[8];
        #pragma unroll
        for (int j = 0; j < 8; j++) { Hr[j] = Hi[j] = 0.f; }
        #pragma unroll 4
        for (int kz = 0; kz < 16; kz++) {
            float2 tz = twz[dz * 17 + kz];
            #pragma unroll
            for (int k = 0; k < 4; k++) {
                float4 g = *(const float4*)(Gb + kz * 32 + k * 2);
                Hr[2 * k]     += g.x * tz.x - g.y * tz.y;
                Hi[2 * k]     += g.x * tz.y + g.y * tz.x;
                Hr[2 * k + 1] += g.z * tz.x - g.w * tz.y;
                Hi[2 * k + 1] += g.z * tz.y + g.w * tz.x;
            }
        }
        float2* hp = sH + (ky * 8 + dz) * 18 + coq * 8;
        #pragma unroll
        for (int k = 0; k < 4; k++)
            *(float4*)(hp + k * 2) = make_float4(Hr[2 * k], Hi[2 * k], Hr[2 * k + 1], Hi[2 * k + 1]);
    }
    __syncthreads();
    // phase Y: out[y][dz][co16] = Re sum_ky twy[y,ky] * H[ky][dz][co16]
    {
        int cog = threadIdx.x & 1, dz = (threadIdx.x >> 1) & 7, yg = threadIdx.x >> 4;
        float acc[4][8];
        #pragma unroll
        for (int yl = 0; yl < 4; yl++)
            #pragma unroll
            for (int cl = 0; cl < 8; cl++) acc[yl][cl] = 0.f;
        const float4* twy4 = (const float4*)twy;
        const float4* sH4 = (const float4*)sH;    // f4 stride 9 per row
        for (int ky = 0; ky < 16; ky++) {
            float4 t0 = twy4[ky * 32 + yg * 2 + 0];
            float4 t1 = twy4[ky * 32 + yg * 2 + 1];
            float4 h0 = sH4[(ky * 8 + dz) * 9 + cog * 4 + 0];
            float4 h1 = sH4[(ky * 8 + dz) * 9 + cog * 4 + 1];
            float4 h2 = sH4[(ky * 8 + dz) * 9 + cog * 4 + 2];
            float4 h3 = sH4[(ky * 8 + dz) * 9 + cog * 4 + 3];
            float tc[4] = {t0.x, t0.z, t1.x, t1.z};
            float ts[4] = {t0.y, t0.w, t1.y, t1.w};
            float hr[8] = {h0.x, h0.z, h1.x, h1.z, h2.x, h2.z, h3.x, h3.z};
            float hi[8] = {h0.y, h0.w, h1.y, h1.w, h2.y, h2.w, h3.y, h3.w};
            #pragma unroll
            for (int yl = 0; yl < 4; yl++)
                #pragma unroll
                for (int cl = 0; cl < 8; cl++)
                    acc[yl][cl] += tc[yl] * hr[cl] - ts[yl] * hi[cl];
        }
        const float sc = 1.0f / 131072.0f;
        #pragma unroll
        for (int yl = 0; yl < 4; yl++) {
            int y = yg * 4 + yl;
            float4* d4 = (float4*)(dstb + ((size_t)y * 64 + zc * 8 + dz) * 32 + ch * 16 + cog * 8);
            d4[0] = make_float4(acc[yl][0] * sc, acc[yl][1] * sc, acc[yl][2] * sc, acc[yl][3] * sc);
            d4[1] = make_float4(acc[yl][4] * sc, acc[yl][5] * sc, acc[yl][6] * sc, acc[yl][7] * sc);
        }
    }
}

extern "C" void kernel_launch(void* const* d_in, const int* in_sizes, int n_in,
                              void* d_out, int out_size, void* d_ws, size_t ws_size,
                              hipStream_t stream) {
    const float* x  = (const float*)d_in[0];
    const float* wr = (const float*)d_in[1];
    const float* wi = (const float*)d_in[2];
    float* out = (float*)d_out;
    char*  ws  = (char*)d_ws;
    // T1: 2,097,152 f2 (16.8 MB); XH: 524,288 f2 (4.2 MB); G: 524,288 f2 (4.2 MB)
    float2* T1 = (float2*)ws;
    float2* XH = (float2*)(ws + (size_t)16777216);
    float2* Gb = (float2*)(ws + (size_t)16777216 + 4194304);

    k_dft_z  <<<1024, 256, 0, stream>>>(x, T1);
    k_dft_y  <<<1024, 256, 0, stream>>>(T1, XH);
    k_mid    <<<1024, 256, 0, stream>>>(XH, wr, wi, Gb);
    k_idft_zy<<<4096, 256, 0, stream>>>(Gb, out);
}